// Round 13
// baseline (355.381 us; speedup 1.0000x reference)
//
#include <hip/hip_runtime.h>
#include <cstdint>
#include <cstddef>

// ExpertMLP: out[e] = gelu(x[e] @ wfc[e]) @ wproj[e]
// E=32, CAP=4096, D=256, H=1024. fp32 in/out, bf16 MFMA internally.
// Round 13 — m97-FAITHFUL GEMMs: 128x128 tile, 256 thr (4 waves, 64x64 wave
// tile, acc 64 regs), BK=32, single-buffered 16KB slabs, plain __syncthreads,
// NO manual waitcnt/setprio. Overlap comes from occupancy (~3 blocks/CU,
// m114 mechanism), the documented 874-912 TF configuration on this chip.

#define NE   32
#define CAPN 4096
#define DDIM 256
#define HDIM 1024

typedef __bf16 bf16x8 __attribute__((ext_vector_type(8)));
typedef __bf16 bf16x4 __attribute__((ext_vector_type(4)));
typedef __bf16 bf16x2 __attribute__((ext_vector_type(2)));
typedef float  f32x4  __attribute__((ext_vector_type(4)));

#define AS1 __attribute__((address_space(1)))
#define AS3 __attribute__((address_space(3)))

__device__ __forceinline__ void gld_lds16(const void* g, void* l) {
  __builtin_amdgcn_global_load_lds((const AS1 uint32_t*)g, (AS3 uint32_t*)l, 16, 0, 0);
}

__device__ __forceinline__ float gelu_f(float x) {
  float x2 = x * x;
  float u  = x * __builtin_fmaf(0.1029432f, x2, 2.3022078f);
  float t  = __builtin_amdgcn_exp2f(u);
  float r  = __builtin_amdgcn_rcpf(t + 1.0f);
  return __builtin_fmaf(-x, r, x);
}

#define MFMA_(a, b, c) __builtin_amdgcn_mfma_f32_16x16x32_bf16(a, b, c, 0, 0, 0)

// ---------------- pre-pass: transpose + cast fp32 -> bf16 -------------------
__global__ __launch_bounds__(256) void tcast_kernel(const float* __restrict__ in,
                                                    __bf16* __restrict__ outp,
                                                    int R, int C) {
  __shared__ __bf16 tl[64][72];
  const int cb = C >> 6;
  const int nb = (R >> 6) * cb;
  const int b  = blockIdx.x;
  const int e  = b / nb;
  const int t  = b - e * nb;
  const int br = t / cb;
  const int bc = t - br * cb;
  const float* src = in + ((size_t)e * R + (size_t)br * 64) * C + (size_t)bc * 64;
#pragma unroll
  for (int i = 0; i < 16; ++i) {
    int idx = i * 256 + threadIdx.x;
    int r = idx >> 6, c = idx & 63;
    tl[c][r] = (__bf16)src[(size_t)r * C + c];
  }
  __syncthreads();
  __bf16* dst = outp + ((size_t)e * C + (size_t)bc * 64) * R + (size_t)br * 64;
#pragma unroll
  for (int i = 0; i < 8; ++i) {
    int idx = i * 512 + threadIdx.x * 2;
    int c = idx >> 6, r = idx & 63;
    bf16x2 p;
    p[0] = tl[c][r];
    p[1] = tl[c][r + 1];
    *(bf16x2*)(dst + (size_t)c * R + r) = p;
  }
}

// ---------------- x fp32 -> bf16 flat cast (all experts, once) --------------
__global__ __launch_bounds__(256) void xcast_kernel(const float* __restrict__ in,
                                                    __bf16* __restrict__ outp,
                                                    long n8) {
  long i = (long)blockIdx.x * 256 + threadIdx.x;
  const long stride = (long)gridDim.x * 256;
  for (; i < n8; i += stride) {
    float4 a0 = ((const float4*)in)[2 * i];
    float4 a1 = ((const float4*)in)[2 * i + 1];
    bf16x8 v;
    v[0] = (__bf16)a0.x; v[1] = (__bf16)a0.y; v[2] = (__bf16)a0.z; v[3] = (__bf16)a0.w;
    v[4] = (__bf16)a1.x; v[5] = (__bf16)a1.y; v[6] = (__bf16)a1.z; v[7] = (__bf16)a1.w;
    ((bf16x8*)outp)[i] = v;
  }
}

// ---------------- m97-shape 128x128 GEMM (BK=32, single-buffer) -------------
// 4 waves: wh=w&1 -> A-row half (64), wm=w>>1 -> B-row half (64).
// acc[rf][fm]: A-row = wh*64+rf*16+(l4*4+j), B-row = wm*64+fm*16+l15 (lane).
// LDS: A slab [128 r][32 k] @0 (8KB), B slab @8192 (8KB); +transpose area.
// Slab row = 4 slots16B, phys slot = s ^ ((row>>1)&3) (src-addr swizzled).
// G1E: A=wfcT rows h (ct), B=Xb rows m (mt) -> H bf16 via LDS transpose+GELU.
// else: A=Hb rows m (mt),  B=wprojT rows d (ct) -> out f32 coalesced (lane=d).
template <int NKT, int NT, int RSA, int RSB, bool G1E>
__global__ __launch_bounds__(256, 3) void gemm97(
    const __bf16* __restrict__ Ap, const __bf16* __restrict__ Bp,
    void* __restrict__ Cp, int e0) {
  __shared__ char smem[32768];
  const int tid = threadIdx.x;
  const int l15 = tid & 15, l4 = (tid >> 4) & 3, w = tid >> 6;
  const int wh = w & 1, wm = w >> 1;

  const int tpe = 32 * NT;
  const int bid = blockIdx.x;
  const int e_l = bid / tpe;
  const int rem = bid - e_l * tpe;
  const int mt  = rem / NT, ct = rem - mt * NT;
  const int m0  = mt << 7, r0 = ct << 7;
  const int e_g = e0 + e_l;

  const __bf16* Ab;
  const __bf16* Bb;
  if constexpr (G1E) {
    Ab = Ap + ((size_t)(e_g * HDIM + r0)) * RSA;   // wfcT rows h
    Bb = Bp + ((size_t)(e_g * CAPN + m0)) * RSB;   // Xb rows m
  } else {
    Ab = Ap + ((size_t)(e_l * CAPN + m0)) * RSA;   // Hb rows m
    Bb = Bp + ((size_t)(e_g * DDIM + r0)) * RSB;   // wprojT rows d
  }

  // staging lane geometry: slots o = tid, tid+256 (rows r, r+64)
  const int srow = tid >> 2;
  const int ssl  = (tid & 3) ^ ((srow >> 1) & 3);
  const size_t ga0 = (size_t)srow * RSA + ssl * 8;
  const size_t ga1 = (size_t)(srow + 64) * RSA + ssl * 8;
  const size_t gb0 = (size_t)srow * RSB + ssl * 8;
  const size_t gb1 = (size_t)(srow + 64) * RSB + ssl * 8;
  char* dA0 = smem + tid * 16;
  char* dA1 = smem + (tid + 256) * 16;
  char* dB0 = smem + 8192 + tid * 16;
  char* dB1 = smem + 8192 + (tid + 256) * 16;

  // fragment read offsets (row stride 64B, swizzled slot)
  const int physk = (l4 ^ ((l15 >> 1) & 3)) * 16;
  const int aoff  = (wh * 64 + l15) * 64 + physk;          // + rf*1024
  const int boff  = 8192 + (wm * 64 + l15) * 64 + physk;   // + fm*1024

  f32x4 zero = 0.0f;
  f32x4 acc[4][4];
#pragma unroll
  for (int a = 0; a < 4; ++a)
#pragma unroll
    for (int b = 0; b < 4; ++b) acc[a][b] = zero;

  for (int kt = 0; kt < NKT; ++kt) {
    const int ko = kt * 32;
    __syncthreads();  // previous step's readers done
    gld_lds16(Ab + ga0 + ko, dA0);
    gld_lds16(Ab + ga1 + ko, dA1);
    gld_lds16(Bb + gb0 + ko, dB0);
    gld_lds16(Bb + gb1 + ko, dB1);
    __syncthreads();  // compiler drains vmcnt before barrier (m97 behavior)
    bf16x8 af[4], bx[4];
#pragma unroll
    for (int rf = 0; rf < 4; ++rf)
      af[rf] = *(const bf16x8*)(smem + aoff + rf * 1024);
#pragma unroll
    for (int fm = 0; fm < 4; ++fm)
      bx[fm] = *(const bf16x8*)(smem + boff + fm * 1024);
#pragma unroll
    for (int rf = 0; rf < 4; ++rf)
#pragma unroll
      for (int fm = 0; fm < 4; ++fm)
        acc[rf][fm] = MFMA_(af[rf], bx[fm], acc[rf][fm]);
  }

  // ---- epilogue ----
  if constexpr (G1E) {
    // GELU -> LDS [128 m][128 h] bf16 swizzled (32KB) -> coalesced H writes
    __syncthreads();  // all slab readers done before overwrite
#pragma unroll
    for (int rf = 0; rf < 4; ++rf) {
#pragma unroll
      for (int fm = 0; fm < 4; ++fm) {
        const int hl = wh * 64 + rf * 16 + l4 * 4;
        const int ml = wm * 64 + fm * 16 + l15;
        bf16x4 hv;
#pragma unroll
        for (int j = 0; j < 4; ++j) hv[j] = (__bf16)gelu_f(acc[rf][fm][j]);
        const int s    = hl >> 3;
        const int half = (hl >> 2) & 1;
        const int phys = (s & 8) | ((s & 7) ^ (ml & 7));
        *(bf16x4*)(smem + ml * 256 + phys * 16 + half * 8) = hv;
      }
    }
    __syncthreads();
    __bf16* Hp = (__bf16*)Cp + ((size_t)(e_l * CAPN + m0)) * HDIM + r0;
#pragma unroll
    for (int i = 0; i < 8; ++i) {
      const int sid = i * 256 + tid;
      const int ml  = sid >> 4;
      const int s   = sid & 15;
      const int phys = (s & 8) | ((s & 7) ^ (ml & 7));
      bf16x8 v = *(const bf16x8*)(smem + ml * 256 + phys * 16);
      *(bf16x8*)(Hp + (size_t)ml * HDIM + s * 8) = v;
    }
  } else {
    // acc reg axis = m rows, lane axis = d -> line-coalesced f32 stores
    float* Op = (float*)Cp + ((size_t)(e_g * CAPN + m0)) * DDIM + r0;
#pragma unroll
    for (int rf = 0; rf < 4; ++rf) {
#pragma unroll
      for (int fm = 0; fm < 4; ++fm) {
        const int d = wm * 64 + fm * 16 + l15;
#pragma unroll
        for (int j = 0; j < 4; ++j) {
          const int m = wh * 64 + rf * 16 + l4 * 4 + j;
          Op[(size_t)m * DDIM + d] = acc[rf][fm][j];
        }
      }
    }
  }
}

extern "C" void kernel_launch(void* const* d_in, const int* in_sizes, int n_in,
                              void* d_out, int out_size, void* d_ws, size_t ws_size,
                              hipStream_t stream) {
  (void)in_sizes; (void)n_in; (void)out_size;
  const float* x     = (const float*)d_in[0];
  const float* wfc   = (const float*)d_in[1];   // [E][D][H]
  const float* wproj = (const float*)d_in[2];   // [E][H][D]
  float* out = (float*)d_out;

  // ws: wfcT 16.8M | wprojT 16.8M | Xb(all E) 67.1M | Hb(ne) ne*8.39M
  const size_t WSZ  = (size_t)NE * DDIM * HDIM * sizeof(__bf16);
  const size_t XSZ  = (size_t)NE * CAPN * DDIM * sizeof(__bf16);
  const size_t HPER = (size_t)CAPN * HDIM * sizeof(__bf16);
  int ne = 16;
  while (ne > 1 && 2 * WSZ + XSZ + (size_t)ne * HPER > ws_size) ne >>= 1;

  __bf16* wfcT   = (__bf16*)d_ws;
  __bf16* wprojT = (__bf16*)((char*)d_ws + WSZ);
  __bf16* Xb     = (__bf16*)((char*)d_ws + 2 * WSZ);
  __bf16* Hb     = (__bf16*)((char*)d_ws + 2 * WSZ + XSZ);

  tcast_kernel<<<dim3(NE * 64), dim3(256), 0, stream>>>(wfc, wfcT, DDIM, HDIM);
  tcast_kernel<<<dim3(NE * 64), dim3(256), 0, stream>>>(wproj, wprojT, HDIM, DDIM);
  xcast_kernel<<<dim3(2048), dim3(256), 0, stream>>>(x, Xb, (long)NE * CAPN * DDIM / 8);

  const int ngroups = NE / ne;
  for (int g = 0; g < ngroups; ++g) {
    const int e0 = g * ne;
    // GEMM1: H = gelu(X @ Wfc): blocks = ne * 32 mt * 8 ht
    gemm97<8, 8, DDIM, DDIM, true>
        <<<dim3(ne * 256), dim3(256), 0, stream>>>(wfcT, Xb, Hb, e0);
    // GEMM2: out = H @ Wproj: blocks = ne * 32 mt * 2 dt
    gemm97<32, 2, HDIM, HDIM, false>
        <<<dim3(ne * 64), dim3(256), 0, stream>>>(Hb, wprojT, out, e0);
  }
}